// Round 1
// baseline (56.329 us; speedup 1.0000x reference)
//
#include <hip/hip_runtime.h>
#include <hip/hip_bf16.h>
#include <stdint.h>

// ---------------------------------------------------------------------------
// GraphicalBranch: out[r] = relu(x[row_r] @ W_self + S_{b_r} @ W_nbr + bias)
//   S_b = sum of the 28 pair-node rows of sample b (fully-connected agg)
//   row_r from lut[(b, pmin, pmax)] built from slicing_tensor
// B=1024, nc2=28, D=512, n=8, MAX_REL=10 -> out rows = 10240
// ---------------------------------------------------------------------------

typedef __bf16 bf16_t;
typedef __bf16 bf16x8 __attribute__((ext_vector_type(8)));
typedef __bf16 bf16x4 __attribute__((ext_vector_type(4)));
typedef float  f32x4  __attribute__((ext_vector_type(4)));

#define D_DIM 512
#define NC2   28
#define NOBJ  8
#define MAXREL 10
#define B_SAMP 1024

__device__ __forceinline__ void gload_lds16(const void* g, void* l) {
  __builtin_amdgcn_global_load_lds(
      (const __attribute__((address_space(1))) unsigned int*)g,
      (__attribute__((address_space(3))) unsigned int*)l, 16, 0, 0);
}

// --- K0: lut[b*64 + i*8 + j] = row index ----------------------------------
__global__ void scatter_lut_kernel(const int* __restrict__ st, int* __restrict__ lut, int N) {
  int i = blockIdx.x * 256 + threadIdx.x;
  if (i < N) {
    int b = st[3*i + 0], r = st[3*i + 1], c = st[3*i + 2];
    lut[b * (NOBJ*NOBJ) + r * NOBJ + c] = i;
  }
}

// --- K1: Wt[n][k] = (bf16) W[k][n]  (both weight matrices) -----------------
__global__ void transpose_convert_kernel(const float* __restrict__ Wself,
                                         const float* __restrict__ Wnbr,
                                         bf16_t* __restrict__ Wst,
                                         bf16_t* __restrict__ Wnt) {
  __shared__ float tile[32][33];
  const float* W  = blockIdx.z ? Wnbr : Wself;
  bf16_t*      Wt = blockIdx.z ? Wnt  : Wst;
  int k0 = blockIdx.x * 32, n0 = blockIdx.y * 32;
  int tx = threadIdx.x & 31, ty = threadIdx.x >> 5;   // 256 threads: ty 0..7
  #pragma unroll
  for (int i = 0; i < 32; i += 8)
    tile[ty + i][tx] = W[(size_t)(k0 + ty + i) * D_DIM + n0 + tx];
  __syncthreads();
  #pragma unroll
  for (int i = 0; i < 32; i += 8)
    Wt[(size_t)(n0 + ty + i) * D_DIM + k0 + tx] = (bf16_t)tile[tx][ty + i];
}

// --- K2: S[b] = sum_{r<28} x[b*28+r][:]  -> bf16 ---------------------------
__global__ void sum_s_kernel(const float* __restrict__ x, bf16_t* __restrict__ Sbf) {
  int b = blockIdx.x;     // 1024
  int t = threadIdx.x;    // 128 -> float4 covers 512
  const float4* xr = (const float4*)(x + (size_t)b * NC2 * D_DIM);
  float4 a = {0.f, 0.f, 0.f, 0.f};
  #pragma unroll
  for (int r = 0; r < NC2; ++r) {
    float4 v = xr[(size_t)r * (D_DIM/4) + t];
    a.x += v.x; a.y += v.y; a.z += v.z; a.w += v.w;
  }
  bf16x4 o = { (bf16_t)a.x, (bf16_t)a.y, (bf16_t)a.z, (bf16_t)a.w };
  *(bf16x4*)(Sbf + (size_t)b * D_DIM + t * 4) = o;
}

// --- K3: Abf[r][:] = (bf16) x[row_r][:]  (fused lut lookup) ----------------
__global__ void gather_rows_kernel(const float* __restrict__ x,
                                   const int* __restrict__ lut,
                                   const int* __restrict__ pairs,
                                   bf16_t* __restrict__ Abf) {
  int r = blockIdx.x;                 // 10240
  int b = r / MAXREL, k = r % MAXREL;
  int p0 = pairs[(size_t)(b * MAXREL + k) * 2 + 0];
  int p1 = pairs[(size_t)(b * MAXREL + k) * 2 + 1];
  int pmin = min(p0, p1), pmax = max(p0, p1);
  int row = lut[b * (NOBJ*NOBJ) + pmin * NOBJ + pmax];
  int t = threadIdx.x;                // 128
  float4 v = ((const float4*)(x + (size_t)row * D_DIM))[t];
  bf16x4 o = { (bf16_t)v.x, (bf16_t)v.y, (bf16_t)v.z, (bf16_t)v.w };
  *(bf16x4*)(Abf + (size_t)r * D_DIM + t * 4) = o;
}

// --- K4/K5: C = A(MxK) @ Bt(NxK)^T, m97-style MFMA GEMM --------------------
// A row-major [M][512] bf16, Bt row-major [N][512] bf16 (Bt[n][k] = B[k][n]).
// EPI 0: store f32 C (the T buffer).  EPI 1: relu(C + T[R/10] + bias) -> out.
template<int EPI>
__global__ __launch_bounds__(256) void gemm_bt_kernel(
    const bf16_t* __restrict__ A, const bf16_t* __restrict__ Bt,
    const float* __restrict__ Tb, const float* __restrict__ bias,
    float* __restrict__ out)
{
  __shared__ __align__(16) bf16_t sA[128 * 32];
  __shared__ __align__(16) bf16_t sB[128 * 32];
  const int tid = threadIdx.x;
  const int w = tid >> 6, l = tid & 63;
  const int m0 = blockIdx.x * 128, n0 = blockIdx.y * 128;
  const int wr = (w >> 1) * 64, wc = (w & 1) * 64;   // 2x2 waves of 64x64
  const int kg = l >> 4, lr = l & 15;

  f32x4 acc[4][4] = {};

  for (int k0 = 0; k0 < D_DIM; k0 += 32) {
    // stage 128x32 bf16 tiles (8 KB each) = 512 x 16B loads, 2 per thread
    #pragma unroll
    for (int it = 0; it < 2; ++it) {
      int idx = it * 256 + tid;
      int row = idx >> 2, ch = idx & 3;               // 4 x 16B per 64B row
      gload_lds16(A  + (size_t)(m0 + row) * D_DIM + k0 + ch * 8,
                  sA + (size_t)(it * 256 + w * 64) * 8);
      gload_lds16(Bt + (size_t)(n0 + row) * D_DIM + k0 + ch * 8,
                  sB + (size_t)(it * 256 + w * 64) * 8);
    }
    __syncthreads();   // includes vmcnt(0) drain of global_load_lds

    bf16x8 af[4], bfr[4];
    #pragma unroll
    for (int m = 0; m < 4; ++m)
      af[m] = *(const bf16x8*)(sA + (wr + m * 16 + lr) * 32 + kg * 8);
    #pragma unroll
    for (int n = 0; n < 4; ++n)
      bfr[n] = *(const bf16x8*)(sB + (wc + n * 16 + lr) * 32 + kg * 8);

    #pragma unroll
    for (int m = 0; m < 4; ++m)
      #pragma unroll
      for (int n = 0; n < 4; ++n)
        acc[m][n] = __builtin_amdgcn_mfma_f32_16x16x32_bf16(af[m], bfr[n], acc[m][n], 0, 0, 0);
    __syncthreads();
  }

  // C/D layout: col = lane&15, row = (lane>>4)*4 + reg  [m89-verified]
  #pragma unroll
  for (int m = 0; m < 4; ++m) {
    #pragma unroll
    for (int n = 0; n < 4; ++n) {
      #pragma unroll
      for (int reg = 0; reg < 4; ++reg) {
        int R = m0 + wr + m * 16 + kg * 4 + reg;
        int C = n0 + wc + n * 16 + lr;
        float v = acc[m][n][reg];
        if (EPI == 0) {
          out[(size_t)R * D_DIM + C] = v;
        } else {
          int bb = R / MAXREL;
          v += Tb[(size_t)bb * D_DIM + C] + bias[C];
          out[(size_t)R * D_DIM + C] = fmaxf(v, 0.0f);
        }
      }
    }
  }
}

extern "C" void kernel_launch(void* const* d_in, const int* in_sizes, int n_in,
                              void* d_out, int out_size, void* d_ws, size_t ws_size,
                              hipStream_t stream) {
  const float* x     = (const float*)d_in[0];   // [28672, 512]
  const float* Wself = (const float*)d_in[1];   // [512, 512]
  const float* Wnbr  = (const float*)d_in[2];   // [512, 512]
  const float* bias  = (const float*)d_in[3];   // [512]
  const int*   st    = (const int*)d_in[4];     // [28672, 3]
  const int*   pairs = (const int*)d_in[5];     // [1024, 10, 2]

  const int Nrows = in_sizes[0] / D_DIM;        // 28672
  const int OutRows = B_SAMP * MAXREL;          // 10240

  // workspace layout (~14.3 MB)
  char* ws = (char*)d_ws;
  size_t off = 0;
  int*    lut = (int*)(ws + off);    off += (size_t)B_SAMP * NOBJ * NOBJ * 4; // 256 KB
  bf16_t* Sbf = (bf16_t*)(ws + off); off += (size_t)B_SAMP * D_DIM * 2;       // 1 MB
  bf16_t* Wst = (bf16_t*)(ws + off); off += (size_t)D_DIM * D_DIM * 2;        // 512 KB
  bf16_t* Wnt = (bf16_t*)(ws + off); off += (size_t)D_DIM * D_DIM * 2;        // 512 KB
  float*  Tb  = (float*)(ws + off);  off += (size_t)B_SAMP * D_DIM * 4;       // 2 MB
  bf16_t* Abf = (bf16_t*)(ws + off); off += (size_t)OutRows * D_DIM * 2;      // 10 MB

  scatter_lut_kernel<<<(Nrows + 255) / 256, 256, 0, stream>>>(st, lut, Nrows);
  transpose_convert_kernel<<<dim3(16, 16, 2), 256, 0, stream>>>(Wself, Wnbr, Wst, Wnt);
  sum_s_kernel<<<B_SAMP, 128, 0, stream>>>(x, Sbf);
  gather_rows_kernel<<<OutRows, 128, 0, stream>>>(x, lut, pairs, Abf);

  // T = S @ W_nbr   (M=1024)
  gemm_bt_kernel<0><<<dim3(B_SAMP / 128, D_DIM / 128), 256, 0, stream>>>(
      Sbf, Wnt, nullptr, nullptr, Tb);
  // out = relu(Abf @ W_self + T[b] + bias)   (M=10240)
  gemm_bt_kernel<1><<<dim3(OutRows / 128, D_DIM / 128), 256, 0, stream>>>(
      Abf, Wst, Tb, bias, (float*)d_out);
}

// Round 2
// 48.549 us; speedup vs baseline: 1.1603x; 1.1603x over previous
//
#include <hip/hip_runtime.h>
#include <hip/hip_bf16.h>
#include <stdint.h>

// ---------------------------------------------------------------------------
// GraphicalBranch: out[r] = relu(x[row_r] @ W_self + S_{b_r} @ W_nbr + bias)
//   S_b = sum of the 28 pair-node rows of sample b (fully-connected agg)
//   row_r from lut[(b, pmin, pmax)] built from slicing_tensor
// B=1024, nc2=28, D=512, n=8, MAX_REL=10 -> out rows = 10240
// 3-kernel fused pipeline:
//   K1 prep:  S-sum | W transposes (f32->bf16) | lut scatter   (independent)
//   K2 mid:   T = S @ W_nbr  |  gather+convert selected rows -> Abf
//   K3 main:  out = relu(Abf @ W_self + T[b] + bias)
// ---------------------------------------------------------------------------

typedef __bf16 bf16_t;
typedef __bf16 bf16x8 __attribute__((ext_vector_type(8)));
typedef __bf16 bf16x4 __attribute__((ext_vector_type(4)));
typedef __bf16 bf16x2 __attribute__((ext_vector_type(2)));
typedef float  f32x4  __attribute__((ext_vector_type(4)));

#define D_DIM 512
#define NC2   28
#define NOBJ  8
#define MAXREL 10
#define B_SAMP 1024
#define OUTROWS (B_SAMP * MAXREL)

__device__ __forceinline__ void gload_lds16(const void* g, void* l) {
  __builtin_amdgcn_global_load_lds(
      (const __attribute__((address_space(1))) unsigned int*)g,
      (__attribute__((address_space(3))) unsigned int*)l, 16, 0, 0);
}

// --- shared 128x128 MFMA GEMM tile body ------------------------------------
// A row-major [M][512] bf16, Bt row-major [N][512] bf16 (Bt[n][k] = B[k][n]).
// EPI 0: store f32 C.  EPI 1: relu(C + Tb[R/10] + bias) -> out.
template<int EPI>
__device__ __forceinline__ void gemm_tile(
    const bf16_t* __restrict__ A, const bf16_t* __restrict__ Bt,
    const float* __restrict__ Tb, const float* __restrict__ bias,
    float* __restrict__ out, int m0, int n0)
{
  __shared__ __align__(16) bf16_t sA[128 * 32];
  __shared__ __align__(16) bf16_t sB[128 * 32];
  const int tid = threadIdx.x;
  const int w = tid >> 6, l = tid & 63;
  const int wr = (w >> 1) * 64, wc = (w & 1) * 64;   // 2x2 waves of 64x64
  const int kg = l >> 4, lr = l & 15;

  f32x4 acc[4][4] = {};

  for (int k0 = 0; k0 < D_DIM; k0 += 32) {
    #pragma unroll
    for (int it = 0; it < 2; ++it) {
      int idx = it * 256 + tid;
      int row = idx >> 2, ch = idx & 3;               // 4 x 16B per 64B row
      gload_lds16(A  + (size_t)(m0 + row) * D_DIM + k0 + ch * 8,
                  sA + (size_t)(it * 256 + w * 64) * 8);
      gload_lds16(Bt + (size_t)(n0 + row) * D_DIM + k0 + ch * 8,
                  sB + (size_t)(it * 256 + w * 64) * 8);
    }
    __syncthreads();

    bf16x8 af[4], bfr[4];
    #pragma unroll
    for (int m = 0; m < 4; ++m)
      af[m] = *(const bf16x8*)(sA + (wr + m * 16 + lr) * 32 + kg * 8);
    #pragma unroll
    for (int n = 0; n < 4; ++n)
      bfr[n] = *(const bf16x8*)(sB + (wc + n * 16 + lr) * 32 + kg * 8);

    #pragma unroll
    for (int m = 0; m < 4; ++m)
      #pragma unroll
      for (int n = 0; n < 4; ++n)
        acc[m][n] = __builtin_amdgcn_mfma_f32_16x16x32_bf16(af[m], bfr[n], acc[m][n], 0, 0, 0);
    __syncthreads();
  }

  // C/D layout: col = lane&15, row = (lane>>4)*4 + reg  [m89-verified]
  #pragma unroll
  for (int m = 0; m < 4; ++m) {
    #pragma unroll
    for (int n = 0; n < 4; ++n) {
      #pragma unroll
      for (int reg = 0; reg < 4; ++reg) {
        int R = m0 + wr + m * 16 + kg * 4 + reg;
        int C = n0 + wc + n * 16 + lr;
        float v = acc[m][n][reg];
        if (EPI == 0) {
          out[(size_t)R * D_DIM + C] = v;
        } else {
          int bb = R / MAXREL;
          v += Tb[(size_t)bb * D_DIM + C] + bias[C];
          out[(size_t)R * D_DIM + C] = fmaxf(v, 0.0f);
        }
      }
    }
  }
}

// --- K1: fused prep (all parts independent) --------------------------------
// blocks [0,1024)        : S[b] = sum of 28 rows -> bf16
// blocks [1024,1536)     : W transpose+convert (256 blocks per matrix)
// blocks [1536,1536+112) : lut scatter
__global__ __launch_bounds__(256) void prep_kernel(
    const float* __restrict__ x, const float* __restrict__ Wself,
    const float* __restrict__ Wnbr, const int* __restrict__ st,
    int* __restrict__ lut, bf16_t* __restrict__ Sbf,
    bf16_t* __restrict__ Wst, bf16_t* __restrict__ Wnt, int Nrows)
{
  __shared__ float tile[32][33];
  const int blk = blockIdx.x, tid = threadIdx.x;
  if (blk < B_SAMP) {
    const float2* xr = (const float2*)(x + (size_t)blk * NC2 * D_DIM);
    float2 a = {0.f, 0.f};
    #pragma unroll
    for (int r = 0; r < NC2; ++r) {
      float2 v = xr[r * (D_DIM / 2) + tid];
      a.x += v.x; a.y += v.y;
    }
    bf16x2 o = { (bf16_t)a.x, (bf16_t)a.y };
    *(bf16x2*)(Sbf + (size_t)blk * D_DIM + tid * 2) = o;
  } else if (blk < B_SAMP + 512) {
    const int t = blk - B_SAMP;
    const float* W  = (t & 256) ? Wnbr : Wself;
    bf16_t*     Wt  = (t & 256) ? Wnt  : Wst;
    const int r = t & 255;
    const int k0 = (r & 15) * 32, n0 = (r >> 4) * 32;
    const int tx = tid & 31, ty = tid >> 5;
    #pragma unroll
    for (int i = 0; i < 32; i += 8)
      tile[ty + i][tx] = W[(size_t)(k0 + ty + i) * D_DIM + n0 + tx];
    __syncthreads();
    #pragma unroll
    for (int i = 0; i < 32; i += 8)
      Wt[(size_t)(n0 + ty + i) * D_DIM + k0 + tx] = (bf16_t)tile[tx][ty + i];
  } else {
    const int i = (blk - B_SAMP - 512) * 256 + tid;
    if (i < Nrows) {
      int b = st[3 * i + 0], r = st[3 * i + 1], c = st[3 * i + 2];
      lut[b * (NOBJ * NOBJ) + r * NOBJ + c] = i;
    }
  }
}

// --- K2: GEMM-T (32 blocks) | gather rows -> Abf (80 blocks) ---------------
__global__ __launch_bounds__(256) void mid_kernel(
    const bf16_t* __restrict__ Sbf, const bf16_t* __restrict__ Wnt,
    float* __restrict__ Tb, const float* __restrict__ x,
    const int* __restrict__ lut, const int* __restrict__ pairs,
    bf16_t* __restrict__ Abf)
{
  if (blockIdx.x < 32) {
    gemm_tile<0>(Sbf, Wnt, nullptr, nullptr, Tb,
                 (blockIdx.x & 7) * 128, (blockIdx.x >> 3) * 128);
  } else {
    __shared__ int glrow[128];
    const int blk = blockIdx.x - 32;        // 0..79
    const int tid = threadIdx.x;
    const int r0 = blk * 128;
    if (tid < 128) {
      int r = r0 + tid;
      int b = r / MAXREL, k = r % MAXREL;
      int p0 = pairs[(size_t)(b * MAXREL + k) * 2 + 0];
      int p1 = pairs[(size_t)(b * MAXREL + k) * 2 + 1];
      int pmin = min(p0, p1), pmax = max(p0, p1);
      glrow[tid] = lut[b * (NOBJ * NOBJ) + pmin * NOBJ + pmax];
    }
    __syncthreads();
    #pragma unroll 4
    for (int i = tid; i < 128 * 128; i += 256) {
      int rl = i >> 7, c = i & 127;
      float4 v = ((const float4*)(x + (size_t)glrow[rl] * D_DIM))[c];
      bf16x4 o = { (bf16_t)v.x, (bf16_t)v.y, (bf16_t)v.z, (bf16_t)v.w };
      *(bf16x4*)(Abf + (size_t)(r0 + rl) * D_DIM + c * 4) = o;
    }
  }
}

// --- K3: main GEMM with fused epilogue -------------------------------------
__global__ __launch_bounds__(256) void main_gemm_kernel(
    const bf16_t* __restrict__ Abf, const bf16_t* __restrict__ Wst,
    const float* __restrict__ Tb, const float* __restrict__ bias,
    float* __restrict__ out)
{
  gemm_tile<1>(Abf, Wst, Tb, bias, out, blockIdx.x * 128, blockIdx.y * 128);
}

extern "C" void kernel_launch(void* const* d_in, const int* in_sizes, int n_in,
                              void* d_out, int out_size, void* d_ws, size_t ws_size,
                              hipStream_t stream) {
  const float* x     = (const float*)d_in[0];   // [28672, 512]
  const float* Wself = (const float*)d_in[1];   // [512, 512]
  const float* Wnbr  = (const float*)d_in[2];   // [512, 512]
  const float* bias  = (const float*)d_in[3];   // [512]
  const int*   st    = (const int*)d_in[4];     // [28672, 3]
  const int*   pairs = (const int*)d_in[5];     // [1024, 10, 2]

  const int Nrows = in_sizes[0] / D_DIM;        // 28672

  // workspace layout (~14.3 MB)
  char* ws = (char*)d_ws;
  size_t off = 0;
  int*    lut = (int*)(ws + off);    off += (size_t)B_SAMP * NOBJ * NOBJ * 4;
  bf16_t* Sbf = (bf16_t*)(ws + off); off += (size_t)B_SAMP * D_DIM * 2;
  bf16_t* Wst = (bf16_t*)(ws + off); off += (size_t)D_DIM * D_DIM * 2;
  bf16_t* Wnt = (bf16_t*)(ws + off); off += (size_t)D_DIM * D_DIM * 2;
  float*  Tb  = (float*)(ws + off);  off += (size_t)B_SAMP * D_DIM * 4;
  bf16_t* Abf = (bf16_t*)(ws + off); off += (size_t)OUTROWS * D_DIM * 2;

  const int scatterBlocks = (Nrows + 255) / 256;              // 112
  prep_kernel<<<B_SAMP + 512 + scatterBlocks, 256, 0, stream>>>(
      x, Wself, Wnbr, st, lut, Sbf, Wst, Wnt, Nrows);
  mid_kernel<<<32 + OUTROWS / 128, 256, 0, stream>>>(
      Sbf, Wnt, Tb, x, lut, pairs, Abf);
  main_gemm_kernel<<<dim3(OUTROWS / 128, D_DIM / 128), 256, 0, stream>>>(
      Abf, Wst, Tb, bias, (float*)d_out);
}

// Round 3
// 40.957 us; speedup vs baseline: 1.3753x; 1.1854x over previous
//
#include <hip/hip_runtime.h>
#include <hip/hip_bf16.h>
#include <stdint.h>

// ---------------------------------------------------------------------------
// GraphicalBranch: out[r] = relu(x[row_r] @ W_self + (S_{b_r} @ W_nbr) + bias)
//   S_b = sum of the 28 pair-node rows of sample b
//   row_r = b*28 + pidx(pmin,pmax)  [analytic triu-lexicographic lut:
//     slicing_tensor = (repeat(arange(B),28), tile(iu,B), tile(ju,B)) is
//     key-independent, so lut[b,i,j] = b*28 + 7i - i(i-1)/2 + (j-i-1)]
// 2-kernel pipeline:
//   K1 prep (1536 blks): [0,1024): S-sum + fused row-gather->Abf (rows are
//                        among the 28 rows being summed); [1024,1536): W^T bf16
//   K2 fused GEMM (64x4 blks): per block 16 samples = 10 strips of rel-rows
//     (@ W_self^T) + 1 strip of S-rows (@ W_nbr^T => T-tile), epilogue
//     out = relu(acc + T[sample] + bias)
// ---------------------------------------------------------------------------

typedef __bf16 bf16_t;
typedef __bf16 bf16x8 __attribute__((ext_vector_type(8)));
typedef __bf16 bf16x2 __attribute__((ext_vector_type(2)));
typedef float  f32x4  __attribute__((ext_vector_type(4)));

#define D_DIM 512
#define NC2   28
#define NOBJ  8
#define MAXREL 10
#define B_SAMP 1024
#define OUTROWS (B_SAMP * MAXREL)

__device__ __forceinline__ void gload_lds16(const void* g, void* l) {
  __builtin_amdgcn_global_load_lds(
      (const __attribute__((address_space(1))) unsigned int*)g,
      (__attribute__((address_space(3))) unsigned int*)l, 16, 0, 0);
}

// --- K1: fused prep --------------------------------------------------------
// blocks [0,1024):     S[b] = sum of 28 rows -> bf16; emit the 10 selected
//                      rows (analytic pidx) as bf16 into Abf while summing
// blocks [1024,1536):  W transpose+convert (256 blocks per matrix)
__global__ __launch_bounds__(256) void prep_kernel(
    const float* __restrict__ x, const float* __restrict__ Wself,
    const float* __restrict__ Wnbr, const int* __restrict__ pairs,
    bf16_t* __restrict__ Sbf, bf16_t* __restrict__ Abf,
    bf16_t* __restrict__ Wst, bf16_t* __restrict__ Wnt)
{
  const int blk = blockIdx.x, tid = threadIdx.x;
  if (blk < B_SAMP) {
    __shared__ int rel_row[MAXREL];
    if (tid < MAXREL) {
      int p0 = pairs[blk * MAXREL * 2 + tid * 2 + 0];
      int p1 = pairs[blk * MAXREL * 2 + tid * 2 + 1];
      int pmin = min(p0, p1), pmax = max(p0, p1);
      rel_row[tid] = 7 * pmin - (pmin * (pmin - 1)) / 2 + (pmax - pmin - 1);
    }
    __syncthreads();
    int rr[MAXREL];
    #pragma unroll
    for (int j = 0; j < MAXREL; ++j) rr[j] = rel_row[j];

    const float2* xr = (const float2*)(x + (size_t)blk * NC2 * D_DIM);
    float2 a = {0.f, 0.f};
    #pragma unroll
    for (int r = 0; r < NC2; ++r) {
      float2 v = xr[r * (D_DIM / 2) + tid];
      a.x += v.x; a.y += v.y;
      bf16x2 o = { (bf16_t)v.x, (bf16_t)v.y };
      #pragma unroll
      for (int j = 0; j < MAXREL; ++j)
        if (rr[j] == r)   // block-uniform condition -> cheap scalar branch
          *(bf16x2*)(Abf + (size_t)(blk * MAXREL + j) * D_DIM + tid * 2) = o;
    }
    bf16x2 o = { (bf16_t)a.x, (bf16_t)a.y };
    *(bf16x2*)(Sbf + (size_t)blk * D_DIM + tid * 2) = o;
  } else {
    __shared__ float tile[32][33];
    const int t = blk - B_SAMP;
    const float* W  = (t & 256) ? Wnbr : Wself;
    bf16_t*     Wt  = (t & 256) ? Wnt  : Wst;
    const int r = t & 255;
    const int k0 = (r & 15) * 32, n0 = (r >> 4) * 32;
    const int tx = tid & 31, ty = tid >> 5;
    #pragma unroll
    for (int i = 0; i < 32; i += 8)
      tile[ty + i][tx] = W[(size_t)(k0 + ty + i) * D_DIM + n0 + tx];
    __syncthreads();
    #pragma unroll
    for (int i = 0; i < 32; i += 8)
      Wt[(size_t)(n0 + ty + i) * D_DIM + k0 + tx] = (bf16_t)tile[tx][ty + i];
  }
}

// --- K2: fused main GEMM ---------------------------------------------------
// Block (blk, ny): 16 samples, out rows [blk*160, +160), cols [ny*128, +128).
// A-tile strips: 0..9 = Abf rel-rows (@Wst), strip 10 = Sbf S-rows (@Wnt -> T).
__global__ __launch_bounds__(256) void fused_gemm_kernel(
    const bf16_t* __restrict__ Abf, const bf16_t* __restrict__ Sbf,
    const bf16_t* __restrict__ Wst, const bf16_t* __restrict__ Wnt,
    const float* __restrict__ bias, float* __restrict__ out)
{
  __shared__ __align__(16) bf16_t sA[176 * 32];      // 11 strips of 16 rows
  __shared__ __align__(16) bf16_t sB[2 * 128 * 32];  // [Wst | Wnt] tiles
  __shared__ float Tt[16][132];                      // T-tile bounce (+pad)

  const int tid = threadIdx.x;
  const int w = tid >> 6, l = tid & 63;
  const int kg = l >> 4, lr = l & 15;
  const int blk = blockIdx.x;            // 0..63
  const int n0 = blockIdx.y * 128;       // 0..3
  const size_t arow0 = (size_t)blk * 160;
  const size_t srow0 = (size_t)blk * 16;

  f32x4 acc[11][2] = {};

  for (int k0 = 0; k0 < D_DIM; k0 += 32) {
    // stage A: 176 rows x 32 cols = 704 x 16B chunks, 3 rounds (last masked)
    #pragma unroll
    for (int rnd = 0; rnd < 3; ++rnd) {
      int idx = rnd * 256 + tid;
      if (idx < 704) {
        int row = idx >> 2, ch = idx & 3;
        const bf16_t* src = (idx < 640)
            ? Abf + (arow0 + row) * D_DIM + k0 + ch * 8
            : Sbf + (srow0 + (row - 160)) * D_DIM + k0 + ch * 8;
        gload_lds16(src, sA + (size_t)idx * 8);
      }
    }
    // stage B: 2 matrices x 128 rows x 4 chunks = 1024 chunks, 4 rounds
    #pragma unroll
    for (int rnd = 0; rnd < 4; ++rnd) {
      int idx = rnd * 256 + tid;
      int mat = idx >> 9, rc = idx & 511, row = rc >> 2, ch = rc & 3;
      const bf16_t* W = mat ? Wnt : Wst;
      gload_lds16(W + (size_t)(n0 + row) * D_DIM + k0 + ch * 8,
                  sB + (size_t)idx * 8);
    }
    __syncthreads();

    bf16x8 af[11], bs[2], bn[2];
    #pragma unroll
    for (int s = 0; s < 11; ++s)
      af[s] = *(const bf16x8*)(sA + (s * 16 + lr) * 32 + kg * 8);
    #pragma unroll
    for (int t = 0; t < 2; ++t) {
      bs[t] = *(const bf16x8*)(sB + (w * 32 + t * 16 + lr) * 32 + kg * 8);
      bn[t] = *(const bf16x8*)(sB + 128 * 32 + (w * 32 + t * 16 + lr) * 32 + kg * 8);
    }
    #pragma unroll
    for (int s = 0; s < 10; ++s)
      #pragma unroll
      for (int t = 0; t < 2; ++t)
        acc[s][t] = __builtin_amdgcn_mfma_f32_16x16x32_bf16(af[s], bs[t], acc[s][t], 0, 0, 0);
    #pragma unroll
    for (int t = 0; t < 2; ++t)
      acc[10][t] = __builtin_amdgcn_mfma_f32_16x16x32_bf16(af[10], bn[t], acc[10][t], 0, 0, 0);
    __syncthreads();
  }

  // T-tile (strip 10) -> LDS  [C/D layout: col = l&15, row = (l>>4)*4+reg]
  #pragma unroll
  for (int t = 0; t < 2; ++t)
    #pragma unroll
    for (int reg = 0; reg < 4; ++reg)
      Tt[kg * 4 + reg][w * 32 + t * 16 + lr] = acc[10][t][reg];
  __syncthreads();

  const float bv0 = bias[n0 + w * 32 + lr];
  const float bv1 = bias[n0 + w * 32 + 16 + lr];
  #pragma unroll
  for (int s = 0; s < 10; ++s) {
    #pragma unroll
    for (int t = 0; t < 2; ++t) {
      #pragma unroll
      for (int reg = 0; reg < 4; ++reg) {
        int g  = (int)arow0 + s * 16 + kg * 4 + reg;   // global rel row
        int ls = g / MAXREL - (int)srow0;              // local sample 0..15
        int c  = w * 32 + t * 16 + lr;                 // col within tile
        float v = acc[s][t][reg] + Tt[ls][c] + (t ? bv1 : bv0);
        out[(size_t)g * D_DIM + n0 + c] = fmaxf(v, 0.0f);
      }
    }
  }
}

extern "C" void kernel_launch(void* const* d_in, const int* in_sizes, int n_in,
                              void* d_out, int out_size, void* d_ws, size_t ws_size,
                              hipStream_t stream) {
  const float* x     = (const float*)d_in[0];   // [28672, 512]
  const float* Wself = (const float*)d_in[1];   // [512, 512]
  const float* Wnbr  = (const float*)d_in[2];   // [512, 512]
  const float* bias  = (const float*)d_in[3];   // [512]
  const int*   pairs = (const int*)d_in[5];     // [1024, 10, 2]

  // workspace layout (~13 MB)
  char* ws = (char*)d_ws;
  size_t off = 0;
  bf16_t* Sbf = (bf16_t*)(ws + off); off += (size_t)B_SAMP * D_DIM * 2;   // 1 MB
  bf16_t* Wst = (bf16_t*)(ws + off); off += (size_t)D_DIM * D_DIM * 2;    // 512 KB
  bf16_t* Wnt = (bf16_t*)(ws + off); off += (size_t)D_DIM * D_DIM * 2;    // 512 KB
  bf16_t* Abf = (bf16_t*)(ws + off); off += (size_t)OUTROWS * D_DIM * 2;  // 10 MB

  prep_kernel<<<B_SAMP + 512, 256, 0, stream>>>(
      x, Wself, Wnbr, pairs, Sbf, Abf, Wst, Wnt);
  fused_gemm_kernel<<<dim3(OUTROWS / 160, D_DIM / 128), 256, 0, stream>>>(
      Abf, Sbf, Wst, Wnt, bias, (float*)d_out);
}

// Round 4
// 36.439 us; speedup vs baseline: 1.5459x; 1.1240x over previous
//
#include <hip/hip_runtime.h>
#include <hip/hip_bf16.h>
#include <stdint.h>

// ---------------------------------------------------------------------------
// GraphicalBranch: out[r] = relu(x[row_r] @ W_self + (S_{b_r} @ W_nbr) + bias)
//   S_b = sum of the 28 pair-node rows of sample b
//   row_r = b*28 + pidx(pmin,pmax), pidx = 7i - i(i-1)/2 + (j-i-1)  [analytic]
// K1 prep (1536 blks): S-sum + fused gather->Abf | W^T -> bf16
// K2 fused GEMM (128x4 blks): 8 samples/block = 5 strips rel-rows (@Wself^T)
//   + 1 strip S-rows (@Wnbr^T -> T tile), 2-phase dbuf staging, XOR-swizzled
//   LDS, epilogue out = relu(acc + T[sample] + bias)
// ---------------------------------------------------------------------------

typedef __bf16 bf16_t;
typedef __bf16 bf16x8 __attribute__((ext_vector_type(8)));
typedef __bf16 bf16x2 __attribute__((ext_vector_type(2)));
typedef float  f32x4  __attribute__((ext_vector_type(4)));

#define D_DIM 512
#define NC2   28
#define NOBJ  8
#define MAXREL 10
#define B_SAMP 1024
#define OUTROWS (B_SAMP * MAXREL)

__device__ __forceinline__ void gload_lds16(const void* g, void* l) {
  __builtin_amdgcn_global_load_lds(
      (const __attribute__((address_space(1))) unsigned int*)g,
      (__attribute__((address_space(3))) unsigned int*)l, 16, 0, 0);
}

// --- K1: fused prep --------------------------------------------------------
__global__ __launch_bounds__(256) void prep_kernel(
    const float* __restrict__ x, const float* __restrict__ Wself,
    const float* __restrict__ Wnbr, const int* __restrict__ pairs,
    bf16_t* __restrict__ Sbf, bf16_t* __restrict__ Abf,
    bf16_t* __restrict__ Wst, bf16_t* __restrict__ Wnt)
{
  const int blk = blockIdx.x, tid = threadIdx.x;
  if (blk < B_SAMP) {
    __shared__ int rel_row[MAXREL];
    if (tid < MAXREL) {
      int p0 = pairs[blk * MAXREL * 2 + tid * 2 + 0];
      int p1 = pairs[blk * MAXREL * 2 + tid * 2 + 1];
      int pmin = min(p0, p1), pmax = max(p0, p1);
      rel_row[tid] = 7 * pmin - (pmin * (pmin - 1)) / 2 + (pmax - pmin - 1);
    }
    __syncthreads();
    int rr[MAXREL];
    #pragma unroll
    for (int j = 0; j < MAXREL; ++j) rr[j] = rel_row[j];

    const float2* xr = (const float2*)(x + (size_t)blk * NC2 * D_DIM);
    float2 a = {0.f, 0.f};
    #pragma unroll
    for (int r = 0; r < NC2; ++r) {
      float2 v = xr[r * (D_DIM / 2) + tid];
      a.x += v.x; a.y += v.y;
      bf16x2 o = { (bf16_t)v.x, (bf16_t)v.y };
      #pragma unroll
      for (int j = 0; j < MAXREL; ++j)
        if (rr[j] == r)   // block-uniform -> scalar branch
          *(bf16x2*)(Abf + (size_t)(blk * MAXREL + j) * D_DIM + tid * 2) = o;
    }
    bf16x2 o = { (bf16_t)a.x, (bf16_t)a.y };
    *(bf16x2*)(Sbf + (size_t)blk * D_DIM + tid * 2) = o;
  } else {
    __shared__ float tile[32][33];
    const int t = blk - B_SAMP;
    const float* W  = (t & 256) ? Wnbr : Wself;
    bf16_t*     Wt  = (t & 256) ? Wnt  : Wst;
    const int r = t & 255;
    const int k0 = (r & 15) * 32, n0 = (r >> 4) * 32;
    const int tx = tid & 31, ty = tid >> 5;
    #pragma unroll
    for (int i = 0; i < 32; i += 8)
      tile[ty + i][tx] = W[(size_t)(k0 + ty + i) * D_DIM + n0 + tx];
    __syncthreads();
    #pragma unroll
    for (int i = 0; i < 32; i += 8)
      Wt[(size_t)(n0 + ty + i) * D_DIM + k0 + tx] = (bf16_t)tile[tx][ty + i];
  }
}

// --- K2: fused main GEMM, 2-phase dbuf, XOR-swizzled LDS -------------------
// Block (bx, by): 8 samples, out rows [bx*80, +80), cols [by*128, +128).
// A strips 0..4 = 80 rel rows (@Wst); strip 5 = 8 S rows (+8 dup pad) @Wnt.
// LDS chunks (16B): LDS[row][c] = G[row][c ^ ((row>>1)&3)]  (involution).
#define SA_BYTES 6144              // 96 rows * 64 B
#define SB_BYTES 16384             // 2 mats * 128 rows * 64 B
__global__ __launch_bounds__(256) void fused_gemm_kernel(
    const bf16_t* __restrict__ Abf, const bf16_t* __restrict__ Sbf,
    const bf16_t* __restrict__ Wst, const bf16_t* __restrict__ Wnt,
    const float* __restrict__ bias, float* __restrict__ out)
{
  __shared__ __align__(16) unsigned char pool[2 * SA_BYTES + 2 * SB_BYTES];

  const int tid = threadIdx.x;
  const int w = tid >> 6, l = tid & 63;
  const int kg = l >> 4, lr = l & 15;
  const int n0 = blockIdx.y * 128;
  const int arow0 = blockIdx.x * 80;
  const int srow0 = blockIdx.x * 8;

  f32x4 acc[6][2] = {};

  // stage one 32-wide K slab into buffer bsel (22 wave-gloads, ~5.5/wave)
  auto STAGE = [&](int bsel, int k0) {
    bf16_t* aB = (bf16_t*)(pool + bsel * SA_BYTES);
    bf16_t* bB = (bf16_t*)(pool + 2 * SA_BYTES + bsel * SB_BYTES);
    #pragma unroll
    for (int r = 0; r < 6; ++r) {
      int slot = r * 4 + w;
      if (slot < 6) {                       // A: 384 chunks
        int c = slot * 64 + l;
        int row = c >> 2, ch = c & 3;
        int sch = ch ^ ((row >> 1) & 3);
        const bf16_t* g = (slot < 5)
            ? Abf + (size_t)(arow0 + row) * D_DIM + k0 + sch * 8
            : Sbf + (size_t)(srow0 + (row & 7)) * D_DIM + k0 + sch * 8;
        gload_lds16(g, aB + (size_t)slot * 512);
      } else if (slot < 22) {               // B: 1024 chunks (Wst|Wnt)
        int c = (slot - 6) * 64 + l;
        int mat = c >> 9, rc = c & 511;
        int row = rc >> 2, ch = rc & 3;
        int sch = ch ^ ((row >> 1) & 3);
        const bf16_t* W = mat ? Wnt : Wst;
        gload_lds16(W + (size_t)(n0 + row) * D_DIM + k0 + sch * 8,
                    bB + (size_t)(slot - 6) * 512);
      }
    }
  };

  STAGE(0, 0);
  __syncthreads();

  const int xorc = (kg ^ ((lr >> 1) & 3)) * 8;   // swizzled chunk -> elem off
  int cur = 0;
  #pragma unroll 2
  for (int t = 0; t < 16; ++t) {
    if (t < 15) STAGE(cur ^ 1, (t + 1) * 32);    // prefetch next slab

    const bf16_t* aC = (const bf16_t*)(pool + cur * SA_BYTES);
    const bf16_t* bC = (const bf16_t*)(pool + 2 * SA_BYTES + cur * SB_BYTES);
    bf16x8 af[6], bs[2], bn[2];
    #pragma unroll
    for (int s = 0; s < 6; ++s)
      af[s] = *(const bf16x8*)(aC + (s * 16 + lr) * 32 + xorc);
    #pragma unroll
    for (int u = 0; u < 2; ++u) {
      bs[u] = *(const bf16x8*)(bC + (w * 32 + u * 16 + lr) * 32 + xorc);
      bn[u] = *(const bf16x8*)(bC + 4096 + (w * 32 + u * 16 + lr) * 32 + xorc);
    }
    #pragma unroll
    for (int s = 0; s < 5; ++s)
      #pragma unroll
      for (int u = 0; u < 2; ++u)
        acc[s][u] = __builtin_amdgcn_mfma_f32_16x16x32_bf16(af[s], bs[u], acc[s][u], 0, 0, 0);
    #pragma unroll
    for (int u = 0; u < 2; ++u)
      acc[5][u] = __builtin_amdgcn_mfma_f32_16x16x32_bf16(af[5], bn[u], acc[5][u], 0, 0, 0);

    __syncthreads();   // drains prefetch vmcnt + fences LDS reads
    cur ^= 1;
  }

  // T tile -> LDS (aliases sA bufs; all reads fenced by final barrier)
  // C/D layout: col = l&15, row = (l>>4)*4 + reg  [m89-verified]
  float* Tt = (float*)pool;                      // [16][132]
  #pragma unroll
  for (int u = 0; u < 2; ++u)
    #pragma unroll
    for (int reg = 0; reg < 4; ++reg)
      Tt[(kg * 4 + reg) * 132 + w * 32 + u * 16 + lr] = acc[5][u][reg];
  __syncthreads();

  const float bv0 = bias[n0 + w * 32 + lr];
  const float bv1 = bias[n0 + w * 32 + 16 + lr];
  #pragma unroll
  for (int s = 0; s < 5; ++s) {
    #pragma unroll
    for (int u = 0; u < 2; ++u) {
      #pragma unroll
      for (int reg = 0; reg < 4; ++reg) {
        int rloc = s * 16 + kg * 4 + reg;        // 0..79
        int ls = rloc / MAXREL;                  // local sample 0..7
        int c = w * 32 + u * 16 + lr;
        float v = acc[s][u][reg] + Tt[ls * 132 + c] + (u ? bv1 : bv0);
        out[(size_t)(arow0 + rloc) * D_DIM + n0 + c] = fmaxf(v, 0.0f);
      }
    }
  }
}

extern "C" void kernel_launch(void* const* d_in, const int* in_sizes, int n_in,
                              void* d_out, int out_size, void* d_ws, size_t ws_size,
                              hipStream_t stream) {
  const float* x     = (const float*)d_in[0];   // [28672, 512]
  const float* Wself = (const float*)d_in[1];   // [512, 512]
  const float* Wnbr  = (const float*)d_in[2];   // [512, 512]
  const float* bias  = (const float*)d_in[3];   // [512]
  const int*   pairs = (const int*)d_in[5];     // [1024, 10, 2]

  char* ws = (char*)d_ws;
  size_t off = 0;
  bf16_t* Sbf = (bf16_t*)(ws + off); off += (size_t)B_SAMP * D_DIM * 2;
  bf16_t* Wst = (bf16_t*)(ws + off); off += (size_t)D_DIM * D_DIM * 2;
  bf16_t* Wnt = (bf16_t*)(ws + off); off += (size_t)D_DIM * D_DIM * 2;
  bf16_t* Abf = (bf16_t*)(ws + off); off += (size_t)OUTROWS * D_DIM * 2;

  prep_kernel<<<B_SAMP + 512, 256, 0, stream>>>(
      x, Wself, Wnbr, pairs, Sbf, Abf, Wst, Wnt);
  fused_gemm_kernel<<<dim3(OUTROWS / 80, D_DIM / 128), 256, 0, stream>>>(
      Abf, Sbf, Wst, Wnt, bias, (float*)d_out);
}